// Round 6
// baseline (94.507 us; speedup 1.0000x reference)
//
#include <hip/hip_runtime.h>

// out[b, i, p] = (i == i2[p] || i == j2[p]) ? NRF[b,p] * 0.5f : 0.0f
// B=1024, N_ATOMS=64, NC2=2016. Pair p = i2*(i2-1)/2 + j2 (j2 < i2).
//
// Fill-shaped linear sweep (R5) + chunked XCD swizzle (T1): block n runs
// on XCD n%8, so swz=(n%8)*4032+n/8 gives each XCD a CONTIGUOUS 1/8 of
// the output (66 MB) whose input slice is 1 MB -> fits per-XCD 4 MB L2,
// cutting input HBM re-fetch ~64 MB -> ~8 MB. Stores remain linear
// nontemporal dwordx4 within each XCD's span.

typedef float f32x4 __attribute__((ext_vector_type(4)));

__device__ __forceinline__ int pair_row(int p) {
    float f = sqrtf(8.0f * (float)p + 1.0f);
    int i = (int)((1.0f + f) * 0.5f);
    while (i * (i - 1) / 2 > p) --i;
    while ((i + 1) * i / 2 <= p) ++i;
    return i;
}

__global__ __launch_bounds__(256) void transform_nrf_kernel(
    const float* __restrict__ nrf, float* __restrict__ out) {
    // Bijective chunked XCD swizzle: 32256 blocks = 8 XCDs * 4032.
    const unsigned bid   = (blockIdx.x % 8u) * 4032u + blockIdx.x / 8u;
    const unsigned wid   = threadIdx.x >> 6;
    const unsigned lane  = threadIdx.x & 63u;
    const unsigned wbase = bid * 1024u + wid * 256u;  // float4 units

    const f32x4* __restrict__ nrf4 = (const f32x4*)nrf;
    f32x4* __restrict__ out4       = (f32x4*)out;

#pragma unroll
    for (int jj = 0; jj < 4; ++jj) {
        const unsigned f   = wbase + jj * 64u + lane;  // flat float4 index
        const unsigned row = f / 504u;                 // b*64 + i (magic div)
        const unsigned p4  = f - row * 504u;
        const unsigned b   = row >> 6;
        const int      i   = (int)(row & 63u);
        const int      p0  = (int)(p4 * 4u);

        const f32x4 v = nrf4[b * 504u + p4];
        const float vv[4] = {v.x * 0.5f, v.y * 0.5f, v.z * 0.5f, v.w * 0.5f};

        int t = pair_row(p0);
        float oo[4];
#pragma unroll
        for (int c = 0; c < 4; ++c) {
            const int p = p0 + c;
            if (c > 0) t += (p >= ((t + 1) * t) / 2) ? 1 : 0;
            const int j2 = p - (t * (t - 1)) / 2;
            oo[c] = ((i == t) || (i == j2)) ? vv[c] : 0.0f;
        }

        f32x4 o = {oo[0], oo[1], oo[2], oo[3]};
        __builtin_nontemporal_store(o, &out4[f]);
    }
}

extern "C" void kernel_launch(void* const* d_in, const int* in_sizes, int n_in,
                              void* d_out, int out_size, void* d_ws, size_t ws_size,
                              hipStream_t stream) {
    const float* nrf = (const float*)d_in[0];
    float* out       = (float*)d_out;
    // 33,030,144 float4 / (256 threads * 4 stores) = 32,256 blocks.
    transform_nrf_kernel<<<32256, 256, 0, stream>>>(nrf, out);
}

// Round 7
// 81.083 us; speedup vs baseline: 1.1656x; 1.1656x over previous
//
#include <hip/hip_runtime.h>

// out[b, i, p] = (i == i2[p] || i == j2[p]) ? NRF[b,p] * 0.5f : 0.0f
// B=1024, N_ATOMS=64, NC2=2016. Pair p = i2*(i2-1)/2 + j2 (j2 < i2).
//
// Fill-shaped linear sweep (R5) + FINE-grained XCD swizzle (g=32):
// permute block ids only within each 256-block super-span so that XCD
// k = n%8 processes the 32 consecutive blocks of one batch-row b
// (32 blocks * 1024 f4 = 64 rows = exactly one b). Input per b (8 KB)
// is then fetched by a single XCD; the global write front remains one
// sliding 4 MB window (8 interleaved 512 KB linear runs), unlike the
// failed 4032-block chunking (R6: 8 fronts 66 MB apart, -10%).

typedef float f32x4 __attribute__((ext_vector_type(4)));

__device__ __forceinline__ int pair_row(int p) {
    float f = sqrtf(8.0f * (float)p + 1.0f);
    int i = (int)((1.0f + f) * 0.5f);
    while (i * (i - 1) / 2 > p) --i;
    while ((i + 1) * i / 2 <= p) ++i;
    return i;
}

__global__ __launch_bounds__(256) void transform_nrf_kernel(
    const float* __restrict__ nrf, float* __restrict__ out) {
    // Within each 256-block super-span: XCD k = n%8 takes run k*32..k*32+31.
    const unsigned n    = blockIdx.x;
    const unsigned bid  = (n & ~255u) + (n % 8u) * 32u + ((n & 255u) >> 3);
    const unsigned wid   = threadIdx.x >> 6;
    const unsigned lane  = threadIdx.x & 63u;
    const unsigned wbase = bid * 1024u + wid * 256u;  // float4 units

    const f32x4* __restrict__ nrf4 = (const f32x4*)nrf;
    f32x4* __restrict__ out4       = (f32x4*)out;

#pragma unroll
    for (int jj = 0; jj < 4; ++jj) {
        const unsigned f   = wbase + jj * 64u + lane;  // flat float4 index
        const unsigned row = f / 504u;                 // b*64 + i (magic div)
        const unsigned p4  = f - row * 504u;
        const unsigned b   = row >> 6;
        const int      i   = (int)(row & 63u);
        const int      p0  = (int)(p4 * 4u);

        const f32x4 v = nrf4[b * 504u + p4];
        const float vv[4] = {v.x * 0.5f, v.y * 0.5f, v.z * 0.5f, v.w * 0.5f};

        int t = pair_row(p0);
        float oo[4];
#pragma unroll
        for (int c = 0; c < 4; ++c) {
            const int p = p0 + c;
            if (c > 0) t += (p >= ((t + 1) * t) / 2) ? 1 : 0;
            const int j2 = p - (t * (t - 1)) / 2;
            oo[c] = ((i == t) || (i == j2)) ? vv[c] : 0.0f;
        }

        f32x4 o = {oo[0], oo[1], oo[2], oo[3]};
        __builtin_nontemporal_store(o, &out4[f]);
    }
}

extern "C" void kernel_launch(void* const* d_in, const int* in_sizes, int n_in,
                              void* d_out, int out_size, void* d_ws, size_t ws_size,
                              hipStream_t stream) {
    const float* nrf = (const float*)d_in[0];
    float* out       = (float*)d_out;
    // 33,030,144 float4 / (256 threads * 4 stores) = 32,256 blocks (%256==0).
    transform_nrf_kernel<<<32256, 256, 0, stream>>>(nrf, out);
}